// Round 18
// baseline (122.818 us; speedup 1.0000x reference)
//
#include <hip/hip_runtime.h>
#include <hip/hip_bf16.h>

#define TT 4096
#define HH 1024
#define II 768
#define EE 8
#define TWOI 1536

typedef __attribute__((ext_vector_type(8))) short bf16x8;
typedef __attribute__((ext_vector_type(8))) unsigned short u16x8;
typedef __attribute__((ext_vector_type(4))) float f32x4;

// static device scratch
__device__ unsigned short g_x_bf[TT * HH];
__device__ unsigned short g_w13_bf[EE * TWOI * HH];   // fragment-chunk order
__device__ unsigned short g_w2_bf[EE * HH * II];      // fragment-chunk order
__device__ unsigned short g_a[EE * TT * II];          // fragment-chunk order
__device__ unsigned short g_opart[2 * TT * HH];       // slot-partial outputs (bf16)
__device__ int g_perm_tok[EE * TT];
__device__ float g_perm_w[EE * TT];
__device__ int g_perm_slot[EE * TT];
__device__ int g_cnt[EE];
__device__ int g_e1[TT];
__device__ int g_e2[TT];
__device__ float g_w1f[TT];
__device__ float g_w2f[TT];

__device__ __forceinline__ unsigned short f2bf(float f) {
  union { float f; unsigned u; } v; v.f = f;
  unsigned r = v.u + 0x7fff + ((v.u >> 16) & 1);   // RNE
  return (unsigned short)(r >> 16);
}

__device__ __forceinline__ float bf2f(unsigned short u) {
  union { unsigned v; float f; } c; c.v = (unsigned)u << 16; return c.f;
}

__device__ __forceinline__ void gload16(const void* g, void* l) {
  __builtin_amdgcn_global_load_lds(
      (const __attribute__((address_space(1))) void*)g,
      (__attribute__((address_space(3))) void*)l, 16, 0, 0);
}

// fused prep: blocks [0,1024) router (4 tokens each, atomic-free);
// blocks [1024,5632): streaming weight cvt. One wave = one 4KB source span,
// per-lane 64B CONTIGUOUS reads (pure stream); the chunk-transpose scatter
// happens on the WRITE side: each lane computes its (chunk,c8,r16) and does
// two 16B stores 256B apart (L2 assembles lines from the 16 temporally
// adjacent row-waves of a jbg group).
// chunk layout (unchanged): 1KB chunk = rows [jbg*16,+16) x k [kb*32,+32);
// lane l' = c8*16+r16 owns 8 bf16 at l'*8.
__global__ __launch_bounds__(256) void k_prep(const float* __restrict__ x,
                                              const float* __restrict__ gw,
                                              const float* __restrict__ w13,
                                              const float* __restrict__ w2) {
  const int b = blockIdx.x;
  const int wv = threadIdx.x >> 6;
  const int lane = threadIdx.x & 63;
  if (b >= 1024) {
    const int s = (b - 1024) * 4 + wv;           // 0..18431 (w13: 0..12287)
    const float* in;
    unsigned short* dstb;
    int nKB, row, pir;
    int sl;
    if (s < 12288) {                             // w13: row = span (64 pieces)
      in = w13; dstb = g_w13_bf; nKB = 32;
      sl = s;
      row = s;
      pir = lane;
    } else {                                     // w2: 48 pieces per row
      in = w2; dstb = g_w2_bf; nKB = 24;
      sl = s - 12288;
      int p = sl * 64 + lane;
      row = p / 48;
      pir = p - row * 48;
    }
    const float* src = in + ((size_t)sl * 64 + lane) * 16;
    float4 v0 = ((const float4*)src)[0];
    float4 v1 = ((const float4*)src)[1];
    float4 v2 = ((const float4*)src)[2];
    float4 v3 = ((const float4*)src)[3];
    const int g0 = 2 * pir;                      // even
    const int kb = g0 >> 2;
    const int c80 = g0 & 3;                      // 0 or 2
    const int jbg = row >> 4, rr = row & 15;
    unsigned short* d =
        dstb + ((size_t)(jbg * nKB + kb)) * 512 + (c80 * 16 + rr) * 8;
    u16x8 o0, o1;
    o0[0] = f2bf(v0.x); o0[1] = f2bf(v0.y); o0[2] = f2bf(v0.z); o0[3] = f2bf(v0.w);
    o0[4] = f2bf(v1.x); o0[5] = f2bf(v1.y); o0[6] = f2bf(v1.z); o0[7] = f2bf(v1.w);
    o1[0] = f2bf(v2.x); o1[1] = f2bf(v2.y); o1[2] = f2bf(v2.z); o1[3] = f2bf(v2.w);
    o1[4] = f2bf(v3.x); o1[5] = f2bf(v3.y); o1[6] = f2bf(v3.z); o1[7] = f2bf(v3.w);
    *(u16x8*)d = o0;
    *(u16x8*)(d + 128) = o1;                     // c8+1 slot, +256B
    return;
  }
  const int t = b * 4 + wv;

  const float* xr = x + (size_t)t * HH + lane * 16;
  float4 xv0 = *(const float4*)(xr + 0);
  float4 xv1 = *(const float4*)(xr + 4);
  float4 xv2 = *(const float4*)(xr + 8);
  float4 xv3 = *(const float4*)(xr + 12);

  unsigned short* xd = g_x_bf + (size_t)t * HH + lane * 16;
  ushort4 o0, o1, o2, o3;
  o0.x = f2bf(xv0.x); o0.y = f2bf(xv0.y); o0.z = f2bf(xv0.z); o0.w = f2bf(xv0.w);
  o1.x = f2bf(xv1.x); o1.y = f2bf(xv1.y); o1.z = f2bf(xv1.z); o1.w = f2bf(xv1.w);
  o2.x = f2bf(xv2.x); o2.y = f2bf(xv2.y); o2.z = f2bf(xv2.z); o2.w = f2bf(xv2.w);
  o3.x = f2bf(xv3.x); o3.y = f2bf(xv3.y); o3.z = f2bf(xv3.z); o3.w = f2bf(xv3.w);
  *(ushort4*)(xd + 0) = o0;
  *(ushort4*)(xd + 4) = o1;
  *(ushort4*)(xd + 8) = o2;
  *(ushort4*)(xd + 12) = o3;

  float lg[EE];
#pragma unroll
  for (int ei = 0; ei < EE; ++ei) {
    const float* gr = gw + ei * HH + lane * 16;
    float4 g0 = *(const float4*)(gr + 0);
    float4 g1 = *(const float4*)(gr + 4);
    float4 g2 = *(const float4*)(gr + 8);
    float4 g3 = *(const float4*)(gr + 12);
    float a = xv0.x * g0.x + xv0.y * g0.y + xv0.z * g0.z + xv0.w * g0.w
            + xv1.x * g1.x + xv1.y * g1.y + xv1.z * g1.z + xv1.w * g1.w
            + xv2.x * g2.x + xv2.y * g2.y + xv2.z * g2.z + xv2.w * g2.w
            + xv3.x * g3.x + xv3.y * g3.y + xv3.z * g3.z + xv3.w * g3.w;
#pragma unroll
    for (int s = 32; s > 0; s >>= 1) a += __shfl_xor(a, s);
    lg[ei] = a;
  }

  if (lane == 0) {
    float mx = lg[0];
#pragma unroll
    for (int ei = 1; ei < EE; ++ei) mx = fmaxf(mx, lg[ei]);
    float p[EE]; float s = 0.f;
#pragma unroll
    for (int ei = 0; ei < EE; ++ei) { p[ei] = expf(lg[ei] - mx); s += p[ei]; }
    float inv = 1.f / s;
    int e1 = 0; float b1 = lg[0];
#pragma unroll
    for (int ei = 1; ei < EE; ++ei) if (lg[ei] > b1) { b1 = lg[ei]; e1 = ei; }
    int e2 = -1; float b2 = -3.0e38f;
#pragma unroll
    for (int ei = 0; ei < EE; ++ei)
      if (ei != e1 && lg[ei] > b2) { b2 = lg[ei]; e2 = ei; }

    g_e1[t] = e1;
    g_e2[t] = e2;
    g_w1f[t] = p[e1] * inv;
    g_w2f[t] = p[e2] * inv;
  }
}

// deterministic compaction: block e gathers its tokens via LDS prefix sum.
__global__ __launch_bounds__(256) void k_compact() {
  const int e = blockIdx.x;
  const int tid = threadIdx.x;
  __shared__ int pre[256];

  const int t0 = tid * (TT / 256);
  int c = 0;
#pragma unroll
  for (int j = 0; j < TT / 256; ++j) {
    int t = t0 + j;
    if (g_e1[t] == e) ++c;
    if (g_e2[t] == e) ++c;
  }
  pre[tid] = c;
  __syncthreads();
  for (int off = 1; off < 256; off <<= 1) {
    int v = (tid >= off) ? pre[tid - off] : 0;
    __syncthreads();
    pre[tid] += v;
    __syncthreads();
  }
  int pos = pre[tid] - c;   // exclusive base
#pragma unroll
  for (int j = 0; j < TT / 256; ++j) {
    int t = t0 + j;
    if (g_e1[t] == e) {
      g_perm_tok[e * TT + pos] = t;
      g_perm_w[e * TT + pos] = g_w1f[t];
      g_perm_slot[e * TT + pos] = 0;
      ++pos;
    }
    if (g_e2[t] == e) {
      g_perm_tok[e * TT + pos] = t;
      g_perm_w[e * TT + pos] = g_w2f[t];
      g_perm_slot[e * TT + pos] = 1;
      ++pos;
    }
  }
  if (tid == 255) g_cnt[e] = pre[255];
}

// GEMM1: expert-pinned XCD swizzle (e=bid&7 -> XCD e keeps w13[e] L2-resident).
// 128x128 tile, 8 waves (2x4 frag each), 3-buffer depth-2 prefetch, counted vmcnt.
__global__ __launch_bounds__(512) void k_gemm1() {
  const int bid = blockIdx.x;
  const int e = bid & 7;
  const int k = bid >> 3;             // 0..59
  const int cb = k % 6;
  const int rowbase = (k / 6) * 128;
  const int cnt = g_cnt[e];
  if (rowbase >= cnt) return;
  const int tid = threadIdx.x;
  const int lane = tid & 63;
  const int wid = tid >> 6;           // 0..7
  const int wm = wid >> 1;            // row quarter
  const int wc = wid & 1;             // col half

  __shared__ uint4 sA[3][512];        // 8KB per buf
  __shared__ uint4 sBg[3][512];
  __shared__ uint4 sBu[3][512];

  const int r16 = lane & 15;
  const int c8 = lane >> 4;
  const int arow = rowbase + wid * 16 + r16;
  const int tok = (arow < cnt) ? g_perm_tok[e * TT + arow] : 0;
  const unsigned short* aptr = g_x_bf + (size_t)tok * HH + c8 * 8;
  const unsigned short* bgp =
      g_w13_bf + ((size_t)(e * 96 + cb * 8 + wid) * 32) * 512 + lane * 8;
  const unsigned short* bup = bgp + (size_t)48 * 32 * 512;

  const int soff = __builtin_amdgcn_readfirstlane(wid * 1024);

#define STG1(buf, kk) do { \
    gload16(aptr + (kk) * 32, (char*)sA + (buf) * 8192 + soff); \
    gload16(bgp + (size_t)(kk) * 512, (char*)sBg + (buf) * 8192 + soff); \
    gload16(bup + (size_t)(kk) * 512, (char*)sBu + (buf) * 8192 + soff); \
  } while (0)

  f32x4 accg[2][4], accu[2][4];
#pragma unroll
  for (int m = 0; m < 2; ++m)
#pragma unroll
    for (int n = 0; n < 4; ++n) {
      accg[m][n] = (f32x4){0.f, 0.f, 0.f, 0.f};
      accu[m][n] = (f32x4){0.f, 0.f, 0.f, 0.f};
    }

  STG1(0, 0);
  STG1(1, 1);
  for (int ks = 0; ks < 32; ++ks) {
    const int cur = ks % 3;
    if (ks < 30) {
      const int stg = (ks + 2) % 3;
      STG1(stg, ks + 2);
      asm volatile("s_waitcnt vmcnt(6)" ::: "memory");
    } else if (ks == 30) {
      asm volatile("s_waitcnt vmcnt(3)" ::: "memory");
    } else {
      asm volatile("s_waitcnt vmcnt(0)" ::: "memory");
    }
    __builtin_amdgcn_s_barrier();
    __builtin_amdgcn_sched_barrier(0);
    bf16x8 af[2], bgf[4], buf_[4];
#pragma unroll
    for (int m = 0; m < 2; ++m)
      af[m] = *(const bf16x8*)((const char*)sA + cur * 8192 + (wm * 2 + m) * 1024 + lane * 16);
#pragma unroll
    for (int n = 0; n < 4; ++n) {
      int jb = wc * 4 + n;
      bgf[n] = *(const bf16x8*)((const char*)sBg + cur * 8192 + jb * 1024 + lane * 16);
      buf_[n] = *(const bf16x8*)((const char*)sBu + cur * 8192 + jb * 1024 + lane * 16);
    }
#pragma unroll
    for (int m = 0; m < 2; ++m)
#pragma unroll
      for (int n = 0; n < 4; ++n) {
        accg[m][n] = __builtin_amdgcn_mfma_f32_16x16x32_bf16(af[m], bgf[n], accg[m][n], 0, 0, 0);
        accu[m][n] = __builtin_amdgcn_mfma_f32_16x16x32_bf16(af[m], buf_[n], accu[m][n], 0, 0, 0);
      }
    __builtin_amdgcn_sched_barrier(0);
    __builtin_amdgcn_s_barrier();
  }
#undef STG1

  // epilogue: write a in fragment-chunk order:
  // a[e][rbl][kb][sub*128 + rr*8 + (clo&7)], kb=(i>>5), sub=(i&31)>>3
  const int rhi = lane >> 4, clo = lane & 15;
  unsigned short* abase = g_a + ((size_t)(e * 256 + (rowbase >> 4)) * 24) * 512;
#pragma unroll
  for (int m = 0; m < 2; ++m) {
#pragma unroll
    for (int jj = 0; jj < 4; ++jj) {
      int rbl = wm * 2 + m;
      int rr = rhi * 4 + jj;
      int row = rowbase + rbl * 16 + rr;
      if (row < cnt) {
#pragma unroll
        for (int n = 0; n < 4; ++n) {
          int kb = cb * 4 + wc * 2 + (n >> 1);
          int sub = (2 * n + (clo >> 3)) & 3;
          float gv = accg[m][n][jj];
          float uv = accu[m][n][jj];
          float av = gv / (1.f + __expf(-gv)) * uv;
          abase[((size_t)rbl * 24 + kb) * 512 + sub * 128 + rr * 8 + (clo & 7)] = f2bf(av);
        }
      }
    }
  }
}

// GEMM2: expert-pinned XCD swizzle; 128x128, 8 waves, 3-buffer depth-2
// prefetch; A and B both chunk-layout; bf16 plain stores to slot partials.
__global__ __launch_bounds__(512) void k_gemm2() {
  const int bid = blockIdx.x;
  const int e = bid & 7;
  const int k = bid >> 3;             // 0..79
  const int cb = k % 8;
  const int rowbase = (k / 8) * 128;
  const int cnt = g_cnt[e];
  if (rowbase >= cnt) return;
  const int tid = threadIdx.x;
  const int lane = tid & 63;
  const int wid = tid >> 6;
  const int wm = wid >> 1;
  const int wc = wid & 1;

  __shared__ uint4 sA[3][512];
  __shared__ uint4 sB[3][512];
  __shared__ int s_tok[128];
  __shared__ float s_w[128];
  __shared__ int s_slot[128];

  if (tid < 128) {
    int row = rowbase + tid;
    bool v = row < cnt;
    s_tok[tid] = v ? g_perm_tok[e * TT + row] : 0;
    s_w[tid] = v ? g_perm_w[e * TT + row] : 0.f;
    s_slot[tid] = v ? g_perm_slot[e * TT + row] : 0;
  }

  const unsigned short* aptr =
      g_a + ((size_t)(e * 256 + (rowbase >> 4) + wid) * 24) * 512 + lane * 8;
  const unsigned short* bp =
      g_w2_bf + ((size_t)(e * 64 + cb * 8 + wid) * 24) * 512 + lane * 8;

  const int soff = __builtin_amdgcn_readfirstlane(wid * 1024);

#define STG2(buf, kk) do { \
    gload16(aptr + (size_t)(kk) * 512, (char*)sA + (buf) * 8192 + soff); \
    gload16(bp + (size_t)(kk) * 512, (char*)sB + (buf) * 8192 + soff); \
  } while (0)

  f32x4 acc[2][4];
#pragma unroll
  for (int m = 0; m < 2; ++m)
#pragma unroll
    for (int n = 0; n < 4; ++n) acc[m][n] = (f32x4){0.f, 0.f, 0.f, 0.f};

  STG2(0, 0);
  STG2(1, 1);
  for (int ks = 0; ks < 24; ++ks) {
    const int cur = ks % 3;
    if (ks < 22) {
      const int stg = (ks + 2) % 3;
      STG2(stg, ks + 2);
      asm volatile("s_waitcnt vmcnt(4)" ::: "memory");
    } else if (ks == 22) {
      asm volatile("s_waitcnt vmcnt(2)" ::: "memory");
    } else {
      asm volatile("s_waitcnt vmcnt(0)" ::: "memory");
    }
    __builtin_amdgcn_s_barrier();
    __builtin_amdgcn_sched_barrier(0);
    bf16x8 af[2], bfr[4];
#pragma unroll
    for (int m = 0; m < 2; ++m)
      af[m] = *(const bf16x8*)((const char*)sA + cur * 8192 + (wm * 2 + m) * 1024 + lane * 16);
#pragma unroll
    for (int n = 0; n < 4; ++n)
      bfr[n] = *(const bf16x8*)((const char*)sB + cur * 8192 + (wc * 4 + n) * 1024 + lane * 16);
#pragma unroll
    for (int m = 0; m < 2; ++m)
#pragma unroll
      for (int n = 0; n < 4; ++n)
        acc[m][n] = __builtin_amdgcn_mfma_f32_16x16x32_bf16(af[m], bfr[n], acc[m][n], 0, 0, 0);
    __builtin_amdgcn_sched_barrier(0);
    __builtin_amdgcn_s_barrier();
  }
#undef STG2

  const int rhi = lane >> 4, clo = lane & 15;
#pragma unroll
  for (int m = 0; m < 2; ++m) {
#pragma unroll
    for (int jj = 0; jj < 4; ++jj) {
      int rloc = wm * 32 + m * 16 + rhi * 4 + jj;
      if (rowbase + rloc < cnt) {
        int tok = s_tok[rloc];
        float w = s_w[rloc];
        unsigned short* orow =
            g_opart + (size_t)s_slot[rloc] * TT * HH + (size_t)tok * HH;
#pragma unroll
        for (int n = 0; n < 4; ++n) {
          int h2 = cb * 128 + wc * 64 + n * 16 + clo;
          orow[h2] = f2bf(w * acc[m][n][jj]);
        }
      }
    }
  }
}

// out = opart[0] + opart[1]  (bf16 partials -> f32 out, 8 elems/thread)
__global__ __launch_bounds__(256) void k_combine(float* __restrict__ out) {
  int idx = (blockIdx.x * 256 + threadIdx.x) * 8;
  u16x8 p0 = *(const u16x8*)(g_opart + idx);
  u16x8 p1 = *(const u16x8*)(g_opart + TT * HH + idx);
  float4 o0, o1;
  o0.x = bf2f(p0[0]) + bf2f(p1[0]);
  o0.y = bf2f(p0[1]) + bf2f(p1[1]);
  o0.z = bf2f(p0[2]) + bf2f(p1[2]);
  o0.w = bf2f(p0[3]) + bf2f(p1[3]);
  o1.x = bf2f(p0[4]) + bf2f(p1[4]);
  o1.y = bf2f(p0[5]) + bf2f(p1[5]);
  o1.z = bf2f(p0[6]) + bf2f(p1[6]);
  o1.w = bf2f(p0[7]) + bf2f(p1[7]);
  *(float4*)(out + idx) = o0;
  *(float4*)(out + idx + 4) = o1;
}

extern "C" void kernel_launch(void* const* d_in, const int* in_sizes, int n_in,
                              void* d_out, int out_size, void* d_ws, size_t ws_size,
                              hipStream_t stream) {
  (void)in_sizes; (void)n_in; (void)d_ws; (void)ws_size; (void)out_size;
  const float* x   = (const float*)d_in[0];
  const float* gw  = (const float*)d_in[1];
  const float* w13 = (const float*)d_in[2];
  const float* w2  = (const float*)d_in[3];
  float* out = (float*)d_out;

  k_prep<<<dim3(5632), dim3(256), 0, stream>>>(x, gw, w13, w2);
  k_compact<<<dim3(EE), dim3(256), 0, stream>>>();
  k_gemm1<<<dim3(480), dim3(512), 0, stream>>>();
  k_gemm2<<<dim3(640), dim3(512), 0, stream>>>();
  k_combine<<<dim3(TT * HH / 2048), dim3(256), 0, stream>>>(out);
}

// Round 19
// 111.721 us; speedup vs baseline: 1.0993x; 1.0993x over previous
//
#include <hip/hip_runtime.h>
#include <hip/hip_bf16.h>

#define TT 4096
#define HH 1024
#define II 768
#define EE 8
#define TWOI 1536

typedef __attribute__((ext_vector_type(8))) short bf16x8;
typedef __attribute__((ext_vector_type(8))) unsigned short u16x8;
typedef __attribute__((ext_vector_type(4))) float f32x4;

// static device scratch
__device__ unsigned short g_x_bf[TT * HH];
__device__ unsigned short g_w13_bf[EE * TWOI * HH];   // fragment-chunk order
__device__ unsigned short g_w2_bf[EE * HH * II];      // fragment-chunk order
__device__ unsigned short g_a[EE * TT * II];          // fragment-chunk order
__device__ unsigned short g_opart[2 * TT * HH];       // slot-partial outputs (bf16)
__device__ int g_perm_tok[EE * TT];
__device__ float g_perm_w[EE * TT];
__device__ int g_perm_slot[EE * TT];
__device__ int g_cnt[EE];
__device__ int g_e1[TT];
__device__ int g_e2[TT];
__device__ float g_w1f[TT];
__device__ float g_w2f[TT];

__device__ __forceinline__ unsigned short f2bf(float f) {
  union { float f; unsigned u; } v; v.f = f;
  unsigned r = v.u + 0x7fff + ((v.u >> 16) & 1);   // RNE
  return (unsigned short)(r >> 16);
}

__device__ __forceinline__ float bf2f(unsigned short u) {
  union { unsigned v; float f; } c; c.v = (unsigned)u << 16; return c.f;
}

__device__ __forceinline__ void gload16(const void* g, void* l) {
  __builtin_amdgcn_global_load_lds(
      (const __attribute__((address_space(1))) void*)g,
      (__attribute__((address_space(3))) void*)l, 16, 0, 0);
}

// LDS-transposed group convert: one block = one 16-row group (contiguous
// NKB*32*16 floats in source). Phase 1: coalesced 32B/lane reads -> bf16 ->
// chunk-ordered LDS (chunk stride 65 granules = 1040B, kb spreads banks).
// Phase 2: linear LDS reads -> contiguous 1KB/wave global stores.
// chunk layout (unchanged): 1KB chunk = rows[16] x k[32]; granule
// g = c8*16+r16 holds 8 bf16 at g*16B.
template<int NKB>
__device__ __forceinline__ void cvt_group(const float* __restrict__ in,
                                          unsigned short* __restrict__ dstb,
                                          int grp, char* lds) {
  const int tid = threadIdx.x;
  const int nfl = NKB * 32 * 16;     // floats per group
  const int ng = nfl / 8;            // granules per group
  const int gpr = NKB * 4;           // granules per row
  const float* src = in + (size_t)grp * nfl;
#pragma unroll
  for (int it = 0; it < ng / 256; ++it) {
    int p = it * 256 + tid;
    float4 a = *(const float4*)(src + (size_t)p * 8);
    float4 c = *(const float4*)(src + (size_t)p * 8 + 4);
    int r = p / gpr;                 // row in group (0..15)
    int cir = p - r * gpr;
    int kb = cir >> 2;
    int c8 = cir & 3;
    u16x8 o;
    o[0] = f2bf(a.x); o[1] = f2bf(a.y); o[2] = f2bf(a.z); o[3] = f2bf(a.w);
    o[4] = f2bf(c.x); o[5] = f2bf(c.y); o[6] = f2bf(c.z); o[7] = f2bf(c.w);
    *(u16x8*)(lds + (size_t)(kb * 65 + c8 * 16 + r) * 16) = o;
  }
  __syncthreads();
#pragma unroll
  for (int it = 0; it < ng / 256; ++it) {
    int q = it * 256 + tid;
    int kb = q >> 6, g = q & 63;
    u16x8 o = *(const u16x8*)(lds + (size_t)(kb * 65 + g) * 16);
    *(u16x8*)(dstb + ((size_t)grp * NKB + kb) * 512 + (size_t)g * 8) = o;
  }
}

// fused prep: blocks [0,1024) router (4 tokens each, atomic-free);
// [1024,1792) w13 groups (768); [1792,2304) w2 groups (512).
__global__ __launch_bounds__(256) void k_prep(const float* __restrict__ x,
                                              const float* __restrict__ gw,
                                              const float* __restrict__ w13,
                                              const float* __restrict__ w2) {
  __shared__ char lds[33280];        // 32 chunks x 1040B
  const int b = blockIdx.x;
  const int wv = threadIdx.x >> 6;
  const int lane = threadIdx.x & 63;
  if (b >= 1024) {
    if (b < 1792) cvt_group<32>(w13, g_w13_bf, b - 1024, lds);
    else          cvt_group<24>(w2,  g_w2_bf,  b - 1792, lds);
    return;
  }
  const int t = b * 4 + wv;

  const float* xr = x + (size_t)t * HH + lane * 16;
  float4 xv0 = *(const float4*)(xr + 0);
  float4 xv1 = *(const float4*)(xr + 4);
  float4 xv2 = *(const float4*)(xr + 8);
  float4 xv3 = *(const float4*)(xr + 12);

  unsigned short* xd = g_x_bf + (size_t)t * HH + lane * 16;
  ushort4 o0, o1, o2, o3;
  o0.x = f2bf(xv0.x); o0.y = f2bf(xv0.y); o0.z = f2bf(xv0.z); o0.w = f2bf(xv0.w);
  o1.x = f2bf(xv1.x); o1.y = f2bf(xv1.y); o1.z = f2bf(xv1.z); o1.w = f2bf(xv1.w);
  o2.x = f2bf(xv2.x); o2.y = f2bf(xv2.y); o2.z = f2bf(xv2.z); o2.w = f2bf(xv2.w);
  o3.x = f2bf(xv3.x); o3.y = f2bf(xv3.y); o3.z = f2bf(xv3.z); o3.w = f2bf(xv3.w);
  *(ushort4*)(xd + 0) = o0;
  *(ushort4*)(xd + 4) = o1;
  *(ushort4*)(xd + 8) = o2;
  *(ushort4*)(xd + 12) = o3;

  float lg[EE];
#pragma unroll
  for (int ei = 0; ei < EE; ++ei) {
    const float* gr = gw + ei * HH + lane * 16;
    float4 g0 = *(const float4*)(gr + 0);
    float4 g1 = *(const float4*)(gr + 4);
    float4 g2 = *(const float4*)(gr + 8);
    float4 g3 = *(const float4*)(gr + 12);
    float a = xv0.x * g0.x + xv0.y * g0.y + xv0.z * g0.z + xv0.w * g0.w
            + xv1.x * g1.x + xv1.y * g1.y + xv1.z * g1.z + xv1.w * g1.w
            + xv2.x * g2.x + xv2.y * g2.y + xv2.z * g2.z + xv2.w * g2.w
            + xv3.x * g3.x + xv3.y * g3.y + xv3.z * g3.z + xv3.w * g3.w;
#pragma unroll
    for (int s = 32; s > 0; s >>= 1) a += __shfl_xor(a, s);
    lg[ei] = a;
  }

  if (lane == 0) {
    float mx = lg[0];
#pragma unroll
    for (int ei = 1; ei < EE; ++ei) mx = fmaxf(mx, lg[ei]);
    float p[EE]; float s = 0.f;
#pragma unroll
    for (int ei = 0; ei < EE; ++ei) { p[ei] = expf(lg[ei] - mx); s += p[ei]; }
    float inv = 1.f / s;
    int e1 = 0; float b1 = lg[0];
#pragma unroll
    for (int ei = 1; ei < EE; ++ei) if (lg[ei] > b1) { b1 = lg[ei]; e1 = ei; }
    int e2 = -1; float b2 = -3.0e38f;
#pragma unroll
    for (int ei = 0; ei < EE; ++ei)
      if (ei != e1 && lg[ei] > b2) { b2 = lg[ei]; e2 = ei; }

    g_e1[t] = e1;
    g_e2[t] = e2;
    g_w1f[t] = p[e1] * inv;
    g_w2f[t] = p[e2] * inv;
  }
}

// deterministic compaction: block e gathers its tokens via LDS prefix sum.
__global__ __launch_bounds__(256) void k_compact() {
  const int e = blockIdx.x;
  const int tid = threadIdx.x;
  __shared__ int pre[256];

  const int t0 = tid * (TT / 256);
  int c = 0;
#pragma unroll
  for (int j = 0; j < TT / 256; ++j) {
    int t = t0 + j;
    if (g_e1[t] == e) ++c;
    if (g_e2[t] == e) ++c;
  }
  pre[tid] = c;
  __syncthreads();
  for (int off = 1; off < 256; off <<= 1) {
    int v = (tid >= off) ? pre[tid - off] : 0;
    __syncthreads();
    pre[tid] += v;
    __syncthreads();
  }
  int pos = pre[tid] - c;   // exclusive base
#pragma unroll
  for (int j = 0; j < TT / 256; ++j) {
    int t = t0 + j;
    if (g_e1[t] == e) {
      g_perm_tok[e * TT + pos] = t;
      g_perm_w[e * TT + pos] = g_w1f[t];
      g_perm_slot[e * TT + pos] = 0;
      ++pos;
    }
    if (g_e2[t] == e) {
      g_perm_tok[e * TT + pos] = t;
      g_perm_w[e * TT + pos] = g_w2f[t];
      g_perm_slot[e * TT + pos] = 1;
      ++pos;
    }
  }
  if (tid == 255) g_cnt[e] = pre[255];
}

// GEMM1: expert-pinned XCD swizzle (e=bid&7 -> XCD e keeps w13[e] L2-resident).
// 128x128 tile, 8 waves (2x4 frag each), 3-buffer depth-2 prefetch, counted vmcnt.
__global__ __launch_bounds__(512) void k_gemm1() {
  const int bid = blockIdx.x;
  const int e = bid & 7;
  const int k = bid >> 3;             // 0..59
  const int cb = k % 6;
  const int rowbase = (k / 6) * 128;
  const int cnt = g_cnt[e];
  if (rowbase >= cnt) return;
  const int tid = threadIdx.x;
  const int lane = tid & 63;
  const int wid = tid >> 6;           // 0..7
  const int wm = wid >> 1;            // row quarter
  const int wc = wid & 1;             // col half

  __shared__ uint4 sA[3][512];        // 8KB per buf
  __shared__ uint4 sBg[3][512];
  __shared__ uint4 sBu[3][512];

  const int r16 = lane & 15;
  const int c8 = lane >> 4;
  const int arow = rowbase + wid * 16 + r16;
  const int tok = (arow < cnt) ? g_perm_tok[e * TT + arow] : 0;
  const unsigned short* aptr = g_x_bf + (size_t)tok * HH + c8 * 8;
  const unsigned short* bgp =
      g_w13_bf + ((size_t)(e * 96 + cb * 8 + wid) * 32) * 512 + lane * 8;
  const unsigned short* bup = bgp + (size_t)48 * 32 * 512;

  const int soff = __builtin_amdgcn_readfirstlane(wid * 1024);

#define STG1(buf, kk) do { \
    gload16(aptr + (kk) * 32, (char*)sA + (buf) * 8192 + soff); \
    gload16(bgp + (size_t)(kk) * 512, (char*)sBg + (buf) * 8192 + soff); \
    gload16(bup + (size_t)(kk) * 512, (char*)sBu + (buf) * 8192 + soff); \
  } while (0)

  f32x4 accg[2][4], accu[2][4];
#pragma unroll
  for (int m = 0; m < 2; ++m)
#pragma unroll
    for (int n = 0; n < 4; ++n) {
      accg[m][n] = (f32x4){0.f, 0.f, 0.f, 0.f};
      accu[m][n] = (f32x4){0.f, 0.f, 0.f, 0.f};
    }

  STG1(0, 0);
  STG1(1, 1);
  for (int ks = 0; ks < 32; ++ks) {
    const int cur = ks % 3;
    if (ks < 30) {
      const int stg = (ks + 2) % 3;
      STG1(stg, ks + 2);
      asm volatile("s_waitcnt vmcnt(6)" ::: "memory");
    } else if (ks == 30) {
      asm volatile("s_waitcnt vmcnt(3)" ::: "memory");
    } else {
      asm volatile("s_waitcnt vmcnt(0)" ::: "memory");
    }
    __builtin_amdgcn_s_barrier();
    __builtin_amdgcn_sched_barrier(0);
    bf16x8 af[2], bgf[4], buf_[4];
#pragma unroll
    for (int m = 0; m < 2; ++m)
      af[m] = *(const bf16x8*)((const char*)sA + cur * 8192 + (wm * 2 + m) * 1024 + lane * 16);
#pragma unroll
    for (int n = 0; n < 4; ++n) {
      int jb = wc * 4 + n;
      bgf[n] = *(const bf16x8*)((const char*)sBg + cur * 8192 + jb * 1024 + lane * 16);
      buf_[n] = *(const bf16x8*)((const char*)sBu + cur * 8192 + jb * 1024 + lane * 16);
    }
#pragma unroll
    for (int m = 0; m < 2; ++m)
#pragma unroll
      for (int n = 0; n < 4; ++n) {
        accg[m][n] = __builtin_amdgcn_mfma_f32_16x16x32_bf16(af[m], bgf[n], accg[m][n], 0, 0, 0);
        accu[m][n] = __builtin_amdgcn_mfma_f32_16x16x32_bf16(af[m], buf_[n], accu[m][n], 0, 0, 0);
      }
    __builtin_amdgcn_sched_barrier(0);
    __builtin_amdgcn_s_barrier();
  }
#undef STG1

  // epilogue: write a in fragment-chunk order:
  // a[e][rbl][kb][sub*128 + rr*8 + (clo&7)], kb=(i>>5), sub=(i&31)>>3
  const int rhi = lane >> 4, clo = lane & 15;
  unsigned short* abase = g_a + ((size_t)(e * 256 + (rowbase >> 4)) * 24) * 512;
#pragma unroll
  for (int m = 0; m < 2; ++m) {
#pragma unroll
    for (int jj = 0; jj < 4; ++jj) {
      int rbl = wm * 2 + m;
      int rr = rhi * 4 + jj;
      int row = rowbase + rbl * 16 + rr;
      if (row < cnt) {
#pragma unroll
        for (int n = 0; n < 4; ++n) {
          int kb = cb * 4 + wc * 2 + (n >> 1);
          int sub = (2 * n + (clo >> 3)) & 3;
          float gv = accg[m][n][jj];
          float uv = accu[m][n][jj];
          float av = gv / (1.f + __expf(-gv)) * uv;
          abase[((size_t)rbl * 24 + kb) * 512 + sub * 128 + rr * 8 + (clo & 7)] = f2bf(av);
        }
      }
    }
  }
}

// GEMM2: expert-pinned XCD swizzle; 128x128, 8 waves, 3-buffer depth-2
// prefetch; A and B both chunk-layout; bf16 plain stores to slot partials.
__global__ __launch_bounds__(512) void k_gemm2() {
  const int bid = blockIdx.x;
  const int e = bid & 7;
  const int k = bid >> 3;             // 0..79
  const int cb = k % 8;
  const int rowbase = (k / 8) * 128;
  const int cnt = g_cnt[e];
  if (rowbase >= cnt) return;
  const int tid = threadIdx.x;
  const int lane = tid & 63;
  const int wid = tid >> 6;
  const int wm = wid >> 1;
  const int wc = wid & 1;

  __shared__ uint4 sA[3][512];
  __shared__ uint4 sB[3][512];
  __shared__ int s_tok[128];
  __shared__ float s_w[128];
  __shared__ int s_slot[128];

  if (tid < 128) {
    int row = rowbase + tid;
    bool v = row < cnt;
    s_tok[tid] = v ? g_perm_tok[e * TT + row] : 0;
    s_w[tid] = v ? g_perm_w[e * TT + row] : 0.f;
    s_slot[tid] = v ? g_perm_slot[e * TT + row] : 0;
  }

  const unsigned short* aptr =
      g_a + ((size_t)(e * 256 + (rowbase >> 4) + wid) * 24) * 512 + lane * 8;
  const unsigned short* bp =
      g_w2_bf + ((size_t)(e * 64 + cb * 8 + wid) * 24) * 512 + lane * 8;

  const int soff = __builtin_amdgcn_readfirstlane(wid * 1024);

#define STG2(buf, kk) do { \
    gload16(aptr + (size_t)(kk) * 512, (char*)sA + (buf) * 8192 + soff); \
    gload16(bp + (size_t)(kk) * 512, (char*)sB + (buf) * 8192 + soff); \
  } while (0)

  f32x4 acc[2][4];
#pragma unroll
  for (int m = 0; m < 2; ++m)
#pragma unroll
    for (int n = 0; n < 4; ++n) acc[m][n] = (f32x4){0.f, 0.f, 0.f, 0.f};

  STG2(0, 0);
  STG2(1, 1);
  for (int ks = 0; ks < 24; ++ks) {
    const int cur = ks % 3;
    if (ks < 22) {
      const int stg = (ks + 2) % 3;
      STG2(stg, ks + 2);
      asm volatile("s_waitcnt vmcnt(4)" ::: "memory");
    } else if (ks == 22) {
      asm volatile("s_waitcnt vmcnt(2)" ::: "memory");
    } else {
      asm volatile("s_waitcnt vmcnt(0)" ::: "memory");
    }
    __builtin_amdgcn_s_barrier();
    __builtin_amdgcn_sched_barrier(0);
    bf16x8 af[2], bfr[4];
#pragma unroll
    for (int m = 0; m < 2; ++m)
      af[m] = *(const bf16x8*)((const char*)sA + cur * 8192 + (wm * 2 + m) * 1024 + lane * 16);
#pragma unroll
    for (int n = 0; n < 4; ++n)
      bfr[n] = *(const bf16x8*)((const char*)sB + cur * 8192 + (wc * 4 + n) * 1024 + lane * 16);
#pragma unroll
    for (int m = 0; m < 2; ++m)
#pragma unroll
      for (int n = 0; n < 4; ++n)
        acc[m][n] = __builtin_amdgcn_mfma_f32_16x16x32_bf16(af[m], bfr[n], acc[m][n], 0, 0, 0);
    __builtin_amdgcn_sched_barrier(0);
    __builtin_amdgcn_s_barrier();
  }
#undef STG2

  const int rhi = lane >> 4, clo = lane & 15;
#pragma unroll
  for (int m = 0; m < 2; ++m) {
#pragma unroll
    for (int jj = 0; jj < 4; ++jj) {
      int rloc = wm * 32 + m * 16 + rhi * 4 + jj;
      if (rowbase + rloc < cnt) {
        int tok = s_tok[rloc];
        float w = s_w[rloc];
        unsigned short* orow =
            g_opart + (size_t)s_slot[rloc] * TT * HH + (size_t)tok * HH;
#pragma unroll
        for (int n = 0; n < 4; ++n) {
          int h2 = cb * 128 + wc * 64 + n * 16 + clo;
          orow[h2] = f2bf(w * acc[m][n][jj]);
        }
      }
    }
  }
}

// out = opart[0] + opart[1]  (bf16 partials -> f32 out, 8 elems/thread)
__global__ __launch_bounds__(256) void k_combine(float* __restrict__ out) {
  int idx = (blockIdx.x * 256 + threadIdx.x) * 8;
  u16x8 p0 = *(const u16x8*)(g_opart + idx);
  u16x8 p1 = *(const u16x8*)(g_opart + TT * HH + idx);
  float4 o0, o1;
  o0.x = bf2f(p0[0]) + bf2f(p1[0]);
  o0.y = bf2f(p0[1]) + bf2f(p1[1]);
  o0.z = bf2f(p0[2]) + bf2f(p1[2]);
  o0.w = bf2f(p0[3]) + bf2f(p1[3]);
  o1.x = bf2f(p0[4]) + bf2f(p1[4]);
  o1.y = bf2f(p0[5]) + bf2f(p1[5]);
  o1.z = bf2f(p0[6]) + bf2f(p1[6]);
  o1.w = bf2f(p0[7]) + bf2f(p1[7]);
  *(float4*)(out + idx) = o0;
  *(float4*)(out + idx + 4) = o1;
}

extern "C" void kernel_launch(void* const* d_in, const int* in_sizes, int n_in,
                              void* d_out, int out_size, void* d_ws, size_t ws_size,
                              hipStream_t stream) {
  (void)in_sizes; (void)n_in; (void)d_ws; (void)ws_size; (void)out_size;
  const float* x   = (const float*)d_in[0];
  const float* gw  = (const float*)d_in[1];
  const float* w13 = (const float*)d_in[2];
  const float* w2  = (const float*)d_in[3];
  float* out = (float*)d_out;

  k_prep<<<dim3(2304), dim3(256), 0, stream>>>(x, gw, w13, w2);
  k_compact<<<dim3(EE), dim3(256), 0, stream>>>();
  k_gemm1<<<dim3(480), dim3(512), 0, stream>>>();
  k_gemm2<<<dim3(640), dim3(512), 0, stream>>>();
  k_combine<<<dim3(TT * HH / 2048), dim3(256), 0, stream>>>(out);
}